// Round 16
// baseline (49.866 us; speedup 1.0000x reference)
//
#include <hip/hip_runtime.h>

typedef float f32x4 __attribute__((ext_vector_type(4)));
typedef int   i32x4 __attribute__((ext_vector_type(4)));
typedef unsigned int u32;

#define HW_N  4096
#define C_N   128
#define G_N   16
#define K_N   2048
#define O_N   256

__device__ __forceinline__ u32 pack4(float a, float b, float c, float d, float inv) {
  int q0 = (int)rintf(a * inv), q1 = (int)rintf(b * inv);
  int q2 = (int)rintf(c * inv), q3 = (int)rintf(d * inv);
  return (u32)(q0 & 255) | ((u32)(q1 & 255) << 8) |
         ((u32)(q2 & 255) << 16) | ((u32)(q3 & 255) << 24);
}

// ---- prep: W2 f32 [256][2048] -> i8 fragment-tiled + per-row scale sw ----
// (verified in R14/R15: absmax 0.0703) frag id = mtile*32 + g*2 + ks2;
// lane l holds row = mtile*16 + (l&15), k = g*128 + ks2*64 + (l>>4)*16 + j.
__global__ void w2q_k(const float* __restrict__ W2, char* __restrict__ w2q,
                      float* __restrict__ sw) {
  int o = blockIdx.x;                  // 0..255
  int l = threadIdx.x;                 // 0..63
  const f32x4* rp = reinterpret_cast<const f32x4*>(W2 + (size_t)o * K_N + l * 32);
  float v[32]; float am = 0.f;
#pragma unroll
  for (int q = 0; q < 8; ++q) {
    f32x4 t = rp[q];
#pragma unroll
    for (int j = 0; j < 4; ++j) { v[q * 4 + j] = t[j]; am = fmaxf(am, fabsf(t[j])); }
  }
#pragma unroll
  for (int s = 1; s < 64; s <<= 1) am = fmaxf(am, __shfl_xor(am, s, 64));
  am = fmaxf(am, 1e-30f);
  float inv = 127.0f / am;
  if (l == 0) sw[o] = am / 127.0f;
#pragma unroll
  for (int c = 0; c < 2; ++c) {
    int k0 = l * 32 + c * 16;
    u32 pk[4];
#pragma unroll
    for (int q = 0; q < 4; ++q)
      pk[q] = pack4(v[c * 16 + q * 4 + 0], v[c * 16 + q * 4 + 1],
                    v[c * 16 + q * 4 + 2], v[c * 16 + q * 4 + 3], inv);
    int frag = (o >> 4) * 32 + (k0 >> 7) * 2 + ((k0 >> 6) & 1);
    int lif  = (o & 15) + ((k0 >> 4) & 3) * 16;
    *reinterpret_cast<i32x4*>(w2q + (size_t)frag * 1024 + lif * 16) =
        *reinterpret_cast<i32x4*>(pk);
  }
}

// ---- main fused kernel: W2-STATIONARY ----
// Wave owns 16 o-rows with its FULL K=2048 i8 W2 slice in 128 VGPRs
// (loaded once). Block = 64 o x 256 px (4 waves, 2 blocks/CU), 4 px-tiles
// of 64: stage/quantize x -> group-invariant bfr -> register-only
// MFMA+fold. Zero global loads in steady state.
__launch_bounds__(256, 2)
__global__ void ccattn_main_k(const float* __restrict__ x,
                              const float* __restrict__ W1,
                              const float* __restrict__ b1,
                              const char* __restrict__ w2q,
                              const float* __restrict__ sw,
                              const float* __restrict__ b2,
                              float* __restrict__ out) {
  __shared__ char  qxT[2][64 * 128];     // 2 x 8 KB, granule-swizzled
  __shared__ float fmT[2][G_N][64];      // 2 x 4 KB
  __shared__ float sxT[2][64];
  __shared__ float lmax[4][64];

  const int tid = threadIdx.x;
  const int bid = blockIdx.x;
  const int ot    = bid & 3;             // o-tile of 64 rows
  const int chunk = bid >> 2;            // 0..127: 256-px chunk
  const int b     = chunk >> 4;
  const int poff  = (chunk & 15) * 256;

  const int w  = tid >> 6;
  const int l  = tid & 63;
  const int lc = l & 15;
  const int lk = l >> 4;
  const int mtile = ot * 4 + w;          // this wave's 16 o-rows

  // ---- A prologue: 32 KB -> 32 i32x4 regs (static indexing only) ----
  const char* abase = w2q + (size_t)mtile * 32768 + l * 16;
  i32x4 A[32];
#pragma unroll
  for (int f = 0; f < 32; ++f)
    A[f] = *reinterpret_cast<const i32x4*>(abase + f * 1024);

  // per-wave output-row constants: o = o0 + i, o0 = mtile*16 + lk*4
  const int o0 = mtile * 16 + lk * 4;
  float swv[4], b2v[4];
#pragma unroll
  for (int i = 0; i < 4; ++i) { swv[i] = sw[o0 + i]; b2v[i] = b2[o0 + i]; }

  // staging thread mapping: px 0..63, channel slice [cq*32, cq*32+32)
  const int px = tid & 63;
  const int cq = tid >> 6;

  const float* xb   = x   + (size_t)b * C_N * HW_N + poff;
  float*       outb = out + (size_t)b * O_N * HW_N + poff;

  float v[4][8];                          // staged x (tile t+1 in flight)
#define STLD(pt)                                                    \
  {                                                                 \
    const float* xp = xb + (pt) * 64 + px;                          \
    _Pragma("unroll")                                               \
    for (int gg = 0; gg < 4; ++gg) {                                \
      _Pragma("unroll")                                             \
      for (int j = 0; j < 8; ++j)                                   \
        v[gg][j] = xp[(size_t)(cq * 32 + gg * 8 + j) * HW_N];       \
    }                                                               \
  }
  STLD(0)

#pragma unroll 1
  for (int pt = 0; pt < 4; ++pt) {
    const int tb = pt & 1;
    // ---- staging: absmax + fm, then per-pixel quantize ----
    {
      float am = 0.f, s[4];
#pragma unroll
      for (int gg = 0; gg < 4; ++gg) {
        s[gg] = b1[cq * 4 + gg];
#pragma unroll
        for (int j = 0; j < 8; ++j) {
          am = fmaxf(am, fabsf(v[gg][j]));
          s[gg] += v[gg][j] * W1[(cq * 4 + gg) * 8 + j];
        }
      }
      lmax[cq][px] = am;
#pragma unroll
      for (int gg = 0; gg < 4; ++gg) fmT[tb][cq * 4 + gg][px] = fmaxf(s[gg], 0.f);
      __syncthreads();
      float amax = fmaxf(fmaxf(fmaxf(lmax[0][px], lmax[1][px]),
                               fmaxf(lmax[2][px], lmax[3][px])), 1e-30f);
      float inv = 127.f / amax;
      if (cq == 0) sxT[tb][px] = amax / 127.f;
#pragma unroll
      for (int gr = 0; gr < 2; ++gr) {   // my 2 granules of 16 channels
        u32 pk[4];
#pragma unroll
        for (int q = 0; q < 4; ++q) {
          int gg = gr * 2 + (q >> 1);
          int j0 = (q & 1) * 4;
          pk[q] = pack4(v[gg][j0], v[gg][j0+1], v[gg][j0+2], v[gg][j0+3], inv);
        }
        int gidx = cq * 2 + gr;
        int byte = px * 128 + ((gidx ^ (px & 7)) << 4);
        *reinterpret_cast<i32x4*>(&qxT[tb][0] + byte) = *reinterpret_cast<i32x4*>(pk);
      }
    }
    __syncthreads();                     // publish qxT/fmT/sxT
    if (pt < 3) STLD(pt + 1)             // T14: issue next stage early

    // ---- bfr: group-invariant B fragments (8 ds_read_b128) ----
    i32x4 bfr[2][4];
#pragma unroll
    for (int ks2 = 0; ks2 < 2; ++ks2)
#pragma unroll
      for (int nf = 0; nf < 4; ++nf) {
        int p    = nf * 16 + lc;
        int gidx = ks2 * 4 + lk;
        int byte = p * 128 + ((gidx ^ (p & 7)) << 4);
        bfr[ks2][nf] = *reinterpret_cast<const i32x4*>(&qxT[tb][0] + byte);
      }

    f32x4 acc[4];
#pragma unroll
    for (int nf = 0; nf < 4; ++nf) acc[nf] = (f32x4){0.f, 0.f, 0.f, 0.f};

    // ---- 16 groups, fully unrolled, register-only ----
    __builtin_amdgcn_s_setprio(1);
#pragma unroll
    for (int g = 0; g < 16; ++g) {
      i32x4 P[4];
#pragma unroll
      for (int nf = 0; nf < 4; ++nf)
        P[nf] = __builtin_amdgcn_mfma_i32_16x16x64_i8(
            A[g * 2], bfr[0][nf], (i32x4){0, 0, 0, 0}, 0, 0, 0);
#pragma unroll
      for (int nf = 0; nf < 4; ++nf)
        P[nf] = __builtin_amdgcn_mfma_i32_16x16x64_i8(
            A[g * 2 + 1], bfr[1][nf], P[nf], 0, 0, 0);
#pragma unroll
      for (int nf = 0; nf < 4; ++nf) {
        float sn = fmT[tb][g][nf * 16 + lc];
#pragma unroll
        for (int i = 0; i < 4; ++i)
          acc[nf][i] += sn * (float)P[nf][i];
      }
    }
    __builtin_amdgcn_s_setprio(0);

    // ---- per-tile epilogue: out = acc*sw*sx + b2 ----
    float sxv[4];
#pragma unroll
    for (int nf = 0; nf < 4; ++nf) sxv[nf] = sxT[tb][nf * 16 + lc];
#pragma unroll
    for (int i = 0; i < 4; ++i) {
#pragma unroll
      for (int nf = 0; nf < 4; ++nf)
        outb[(size_t)(o0 + i) * HW_N + pt * 64 + nf * 16 + lc] =
            acc[nf][i] * swv[i] * sxv[nf] + b2v[i];
    }
    __syncthreads();                     // all waves done with buf tb
  }
#undef STLD
}

extern "C" void kernel_launch(void* const* d_in, const int* in_sizes, int n_in,
                              void* d_out, int out_size, void* d_ws, size_t ws_size,
                              hipStream_t stream) {
  const float* x  = (const float*)d_in[0];
  const float* W1 = (const float*)d_in[1];
  const float* b1 = (const float*)d_in[2];
  const float* W2 = (const float*)d_in[3];
  const float* b2 = (const float*)d_in[4];
  float* out = (float*)d_out;
  char*  w2q = (char*)d_ws;                       // 512 KB i8 tiled W2
  float* sw  = (float*)((char*)d_ws + 524288);    // 256 f32 row scales

  w2q_k<<<256, 64, 0, stream>>>(W2, w2q, sw);
  ccattn_main_k<<<512, 256, 0, stream>>>(x, W1, b1, w2q, sw, b2, out);
}

// Round 17
// 36.732 us; speedup vs baseline: 1.3576x; 1.3576x over previous
//
#include <hip/hip_runtime.h>

typedef float f32x4 __attribute__((ext_vector_type(4)));
typedef int   i32x4 __attribute__((ext_vector_type(4)));
typedef unsigned int u32;

#define HW_N  4096
#define C_N   128
#define G_N   16
#define K_N   2048
#define O_N   256
#define BN    128

typedef const __attribute__((address_space(1))) u32 gbl_u32;
typedef __attribute__((address_space(3))) u32 lds_u32;

__device__ __forceinline__ u32 pack4(float a, float b, float c, float d, float inv) {
  int q0 = (int)rintf(a * inv), q1 = (int)rintf(b * inv);
  int q2 = (int)rintf(c * inv), q3 = (int)rintf(d * inv);
  return (u32)(q0 & 255) | ((u32)(q1 & 255) << 8) |
         ((u32)(q2 & 255) << 16) | ((u32)(q3 & 255) << 24);
}

// ---- prep: W2 f32 [256][2048] -> i8, GROUP-MAJOR LDS image + row scale sw --
// byte = g*32768 + (o>>4)*2048 + ks2*1024 + lif*16,
// lif = (o&15) + ((k0>>4)&3)*16  (same fragment layout as R14, regrouped so
// each (g, mt-half) is one contiguous 16 KB tile for global_load_lds).
__global__ void w2q_k(const float* __restrict__ W2, char* __restrict__ w2q,
                      float* __restrict__ sw) {
  int o = blockIdx.x;                  // 0..255
  int l = threadIdx.x;                 // 0..63
  const f32x4* rp = reinterpret_cast<const f32x4*>(W2 + (size_t)o * K_N + l * 32);
  float v[32]; float am = 0.f;
#pragma unroll
  for (int q = 0; q < 8; ++q) {
    f32x4 t = rp[q];
#pragma unroll
    for (int j = 0; j < 4; ++j) { v[q * 4 + j] = t[j]; am = fmaxf(am, fabsf(t[j])); }
  }
#pragma unroll
  for (int s = 1; s < 64; s <<= 1) am = fmaxf(am, __shfl_xor(am, s, 64));
  am = fmaxf(am, 1e-30f);
  float inv = 127.0f / am;
  if (l == 0) sw[o] = am / 127.0f;
#pragma unroll
  for (int c = 0; c < 2; ++c) {
    int k0 = l * 32 + c * 16;
    u32 pk[4];
#pragma unroll
    for (int q = 0; q < 4; ++q)
      pk[q] = pack4(v[c * 16 + q * 4 + 0], v[c * 16 + q * 4 + 1],
                    v[c * 16 + q * 4 + 2], v[c * 16 + q * 4 + 3], inv);
    int g   = k0 >> 7;
    int ks2 = (k0 >> 6) & 1;
    int lif = (o & 15) + ((k0 >> 4) & 3) * 16;
    *reinterpret_cast<i32x4*>(w2q + (size_t)g * 32768 + (o >> 4) * 2048 +
                              ks2 * 1024 + lif * 16) = *reinterpret_cast<i32x4*>(pk);
  }
}

// ---- main fused kernel ----
// out[o,p] = b2[o] + sw[o]*sx[p] * sum_g fm[g,p] * P_g[o,p]  (i8 MFMA)
// Block: 128 o x 128 px, 4 waves (2wm x 2wn), wave 64x64. A staged ONCE
// per block per group into LDS via global_load_lds (16 KB/group/CU instead
// of 64-128 KB through the per-wave L1 return path = the R2-R15 wall).
// 2-slot dbuf, one __syncthreads per group, stage-ahead 1. 2 blocks/CU.
__launch_bounds__(256, 2)
__global__ void ccattn_main_k(const float* __restrict__ x,
                              const float* __restrict__ W1,
                              const float* __restrict__ b1,
                              const char* __restrict__ w2q,
                              const float* __restrict__ sw,
                              const float* __restrict__ b2,
                              float* __restrict__ out) {
  __shared__ __align__(16) char Albs[2][16384];   // 32 KB A dbuf
  __shared__ char  qxT[BN * 128];      // 16 KB, [px][c] i8, granule-swizzled
  __shared__ float fmT[G_N][BN];       // 8 KB
  __shared__ float sxT[BN];
  __shared__ float lmax[2][BN];

  const int tid = threadIdx.x;
  const int bid = blockIdx.x;
  const int mt  = bid >> 8;            // pt-major: co-resident blocks share mt
  const int pt  = bid & 255;
  const int b   = pt >> 5;
  const int px0 = (pt & 31) * BN;

  const int w = tid >> 6;
  const int l = tid & 63;

  // stage group g's 16 KB A tile (this block's mt half): 4 x 1 KB per wave
  auto stage = [&](int g, int slot) {
    const char* src = w2q + (size_t)g * 32768 + mt * 16384 + w * 4096 + l * 16;
    char* dst = &Albs[slot][w * 4096];
#pragma unroll
    for (int r = 0; r < 4; ++r)
      __builtin_amdgcn_global_load_lds((gbl_u32*)(src + r * 1024),
                                       (lds_u32*)(dst + r * 1024), 16, 0, 0);
  };
  stage(0, 0);                         // in flight under x staging
  stage(1, 1);

  const float* xb = x + (size_t)b * C_N * HW_N + px0;

  // ---- staging pass A: read x (exact f32), fm, per-half absmax ----
  const int px    = tid & 127;
  const int chalf = tid >> 7;          // channels [0,64) or [64,128)
  float v[8][8];
  {
    float am = 0.f;
#pragma unroll
    for (int gg = 0; gg < 8; ++gg) {
      const int g  = chalf * 8 + gg;
      const int c0 = g * 8;
      float s = b1[g];
#pragma unroll
      for (int j = 0; j < 8; ++j) {
        float t = xb[(size_t)(c0 + j) * HW_N + px];
        v[gg][j] = t;
        s += t * W1[g * 8 + j];
        am = fmaxf(am, fabsf(t));
      }
      fmT[g][px] = fmaxf(s, 0.0f);
    }
    lmax[chalf][px] = am;
  }
  __syncthreads();

  // ---- staging pass B: per-pixel scale + quantize to qxT ----
  {
    float amax = fmaxf(fmaxf(lmax[0][px], lmax[1][px]), 1e-30f);
    float inv  = 127.0f / amax;
    if (!chalf) sxT[px] = amax / 127.0f;
#pragma unroll
    for (int gr = 0; gr < 4; ++gr) {   // 4 granules of 16 channels each
      u32 pk[4];
#pragma unroll
      for (int q = 0; q < 4; ++q) {
        const int gg = gr * 2 + (q >> 1);
        const int j0 = (q & 1) * 4;
        pk[q] = pack4(v[gg][j0], v[gg][j0 + 1], v[gg][j0 + 2], v[gg][j0 + 3], inv);
      }
      int gidx = chalf * 4 + gr;
      int byte = px * 128 + ((gidx ^ (px & 7)) << 4);
      *reinterpret_cast<i32x4*>(qxT + byte) = *reinterpret_cast<i32x4*>(pk);
    }
  }
  __syncthreads();                     // qxT/fmT ready; slots 0,1 landed

  // ---- wave decomposition ----
  const int wm = w & 1;                // o offset 0/64
  const int wn = w >> 1;               // px offset 0/64
  const int lc = l & 15;
  const int lk = l >> 4;

  // ---- B-fragment register cache [ks2][nf] (group-invariant) ----
  i32x4 bfr[2][4];
#pragma unroll
  for (int ks2 = 0; ks2 < 2; ++ks2)
#pragma unroll
    for (int nf = 0; nf < 4; ++nf) {
      int p    = wn * 64 + nf * 16 + lc;
      int gidx = ks2 * 4 + lk;
      int byte = p * 128 + ((gidx ^ (p & 7)) << 4);
      bfr[ks2][nf] = *reinterpret_cast<const i32x4*>(qxT + byte);
    }

  f32x4 acc[4][4];
#pragma unroll
  for (int mf = 0; mf < 4; ++mf)
#pragma unroll
    for (int nf = 0; nf < 4; ++nf) acc[mf][nf] = (f32x4){0.f, 0.f, 0.f, 0.f};

  // ---- main loop: 16 groups; ds_read A frags, MFMA+fold, 1 barrier/group --
#pragma unroll 1
  for (int g = 0; g < 16; ++g) {
    const char* ab = &Albs[g & 1][(size_t)wm * 8192];
    i32x4 afr[8];                      // [mf*2 + ks2]
#pragma unroll
    for (int mf = 0; mf < 4; ++mf) {
      afr[mf * 2]     = *reinterpret_cast<const i32x4*>(ab + mf * 2048 + l * 16);
      afr[mf * 2 + 1] = *reinterpret_cast<const i32x4*>(ab + mf * 2048 + 1024 + l * 16);
    }
    float sn[4];
#pragma unroll
    for (int nf = 0; nf < 4; ++nf) sn[nf] = fmT[g][wn * 64 + nf * 16 + lc];

    __builtin_amdgcn_s_setprio(1);
#pragma unroll
    for (int nf = 0; nf < 4; ++nf) {
      i32x4 P[4];
#pragma unroll
      for (int mf = 0; mf < 4; ++mf)
        P[mf] = __builtin_amdgcn_mfma_i32_16x16x64_i8(
            afr[mf * 2], bfr[0][nf], (i32x4){0, 0, 0, 0}, 0, 0, 0);
#pragma unroll
      for (int mf = 0; mf < 4; ++mf)
        P[mf] = __builtin_amdgcn_mfma_i32_16x16x64_i8(
            afr[mf * 2 + 1], bfr[1][nf], P[mf], 0, 0, 0);
#pragma unroll
      for (int mf = 0; mf < 4; ++mf) {
#pragma unroll
        for (int i = 0; i < 4; ++i)
          acc[mf][nf][i] += sn[nf] * (float)P[mf][i];
      }
    }
    __builtin_amdgcn_s_setprio(0);

    // barrier: all waves done reading slot g&1 AND (implicit vmcnt(0) drain)
    // stage(g+1) landed for the next iteration. Then refill slot g&1.
    __syncthreads();
    if (g + 2 < 16) stage(g + 2, g & 1);
  }

  // ---- epilogue: out = acc*sw[o]*sx[p] + b2[o] ----
  float sxv[4];
#pragma unroll
  for (int nf = 0; nf < 4; ++nf) sxv[nf] = sxT[wn * 64 + nf * 16 + lc];
  float* outb = out + (size_t)b * O_N * HW_N + px0;
#pragma unroll
  for (int mf = 0; mf < 4; ++mf) {
    int o0 = mt * 128 + wm * 64 + mf * 16 + lk * 4;
#pragma unroll
    for (int i = 0; i < 4; ++i) {
      float so   = sw[o0 + i];
      float bias = b2[o0 + i];
#pragma unroll
      for (int nf = 0; nf < 4; ++nf) {
        int p = wn * 64 + nf * 16 + lc;
        outb[(size_t)(o0 + i) * HW_N + p] = acc[mf][nf][i] * so * sxv[nf] + bias;
      }
    }
  }
}

extern "C" void kernel_launch(void* const* d_in, const int* in_sizes, int n_in,
                              void* d_out, int out_size, void* d_ws, size_t ws_size,
                              hipStream_t stream) {
  const float* x  = (const float*)d_in[0];
  const float* W1 = (const float*)d_in[1];
  const float* b1 = (const float*)d_in[2];
  const float* W2 = (const float*)d_in[3];
  const float* b2 = (const float*)d_in[4];
  float* out = (float*)d_out;
  char*  w2q = (char*)d_ws;                       // 512 KB i8 tiled W2
  float* sw  = (float*)((char*)d_ws + 524288);    // 256 f32 row scales

  w2q_k<<<256, 64, 0, stream>>>(W2, w2q, sw);
  ccattn_main_k<<<512, 256, 0, stream>>>(x, W1, b1, w2q, sw, b2, out);
}

// Round 18
// 35.398 us; speedup vs baseline: 1.4087x; 1.0377x over previous
//
#include <hip/hip_runtime.h>

typedef float f32x4 __attribute__((ext_vector_type(4)));
typedef int   i32x4 __attribute__((ext_vector_type(4)));
typedef unsigned int u32;

#define HW_N  4096
#define C_N   128
#define G_N   16
#define K_N   2048
#define O_N   256
#define BN    128

typedef const __attribute__((address_space(1))) u32 gbl_u32;
typedef __attribute__((address_space(3))) u32 lds_u32;

__device__ __forceinline__ u32 pack4(float a, float b, float c, float d, float inv) {
  int q0 = (int)rintf(a * inv), q1 = (int)rintf(b * inv);
  int q2 = (int)rintf(c * inv), q3 = (int)rintf(d * inv);
  return (u32)(q0 & 255) | ((u32)(q1 & 255) << 8) |
         ((u32)(q2 & 255) << 16) | ((u32)(q3 & 255) << 24);
}

// ---- prep: W2 f32 [256][2048] -> i8, GROUP-MAJOR LDS image + row scale sw --
// byte = g*32768 + (o>>4)*2048 + ks2*1024 + lif*16,
// lif = (o&15) + ((k0>>4)&3)*16  (verified R17: absmax 0.0703)
__global__ void w2q_k(const float* __restrict__ W2, char* __restrict__ w2q,
                      float* __restrict__ sw) {
  int o = blockIdx.x;                  // 0..255
  int l = threadIdx.x;                 // 0..63
  const f32x4* rp = reinterpret_cast<const f32x4*>(W2 + (size_t)o * K_N + l * 32);
  float v[32]; float am = 0.f;
#pragma unroll
  for (int q = 0; q < 8; ++q) {
    f32x4 t = rp[q];
#pragma unroll
    for (int j = 0; j < 4; ++j) { v[q * 4 + j] = t[j]; am = fmaxf(am, fabsf(t[j])); }
  }
#pragma unroll
  for (int s = 1; s < 64; s <<= 1) am = fmaxf(am, __shfl_xor(am, s, 64));
  am = fmaxf(am, 1e-30f);
  float inv = 127.0f / am;
  if (l == 0) sw[o] = am / 127.0f;
#pragma unroll
  for (int c = 0; c < 2; ++c) {
    int k0 = l * 32 + c * 16;
    u32 pk[4];
#pragma unroll
    for (int q = 0; q < 4; ++q)
      pk[q] = pack4(v[c * 16 + q * 4 + 0], v[c * 16 + q * 4 + 1],
                    v[c * 16 + q * 4 + 2], v[c * 16 + q * 4 + 3], inv);
    int g   = k0 >> 7;
    int ks2 = (k0 >> 6) & 1;
    int lif = (o & 15) + ((k0 >> 4) & 3) * 16;
    *reinterpret_cast<i32x4*>(w2q + (size_t)g * 32768 + (o >> 4) * 2048 +
                              ks2 * 1024 + lif * 16) = *reinterpret_cast<i32x4*>(pk);
  }
}

// ---- main fused kernel ----
// R17 structure + afr software pipelining (split barrier, counted waits).
// Per group: {lgkm0; vm0; s_barrier; ds_read afr(g+1); stage(g+2); MFMA+fold}.
// Slot hazards: stage(g+2)->slot g&1 is safe because all waves' afr(g) reads
// (of slot g&1) completed before the barrier (each wave's lgkmcnt(0));
// afr(g+1) reads slot (g+1)&1 whose stage(g+1) is published by the barrier
// (each wave's vmcnt(0)); next overwrite of that slot is stage(g+3), which
// issues only after the g+1 barrier, i.e. after our reads complete.
__launch_bounds__(256, 2)
__global__ void ccattn_main_k(const float* __restrict__ x,
                              const float* __restrict__ W1,
                              const float* __restrict__ b1,
                              const char* __restrict__ w2q,
                              const float* __restrict__ sw,
                              const float* __restrict__ b2,
                              float* __restrict__ out) {
  __shared__ __align__(16) char Albs[2][16384];   // 32 KB A dbuf
  __shared__ char  qxT[BN * 128];      // 16 KB, [px][c] i8, granule-swizzled
  __shared__ float fmT[G_N][BN];       // 8 KB
  __shared__ float sxT[BN];
  __shared__ float lmax[2][BN];

  const int tid = threadIdx.x;
  const int bid = blockIdx.x;
  const int mt  = bid >> 8;            // pt-major: co-resident blocks share mt
  const int pt  = bid & 255;
  const int b   = pt >> 5;
  const int px0 = (pt & 31) * BN;

  const int w = tid >> 6;
  const int l = tid & 63;

  // stage group g's 16 KB A tile (this block's mt half): 4 x 1 KB per wave
  auto stage = [&](int g, int slot) {
    const char* src = w2q + (size_t)g * 32768 + mt * 16384 + w * 4096 + l * 16;
    char* dst = &Albs[slot][w * 4096];
#pragma unroll
    for (int r = 0; r < 4; ++r)
      __builtin_amdgcn_global_load_lds((gbl_u32*)(src + r * 1024),
                                       (lds_u32*)(dst + r * 1024), 16, 0, 0);
  };
  stage(0, 0);                         // in flight under x staging
  stage(1, 1);

  const float* xb = x + (size_t)b * C_N * HW_N + px0;

  // ---- staging pass A: read x (exact f32), fm, per-half absmax ----
  const int px    = tid & 127;
  const int chalf = tid >> 7;          // channels [0,64) or [64,128)
  float v[8][8];
  {
    float am = 0.f;
#pragma unroll
    for (int gg = 0; gg < 8; ++gg) {
      const int g  = chalf * 8 + gg;
      const int c0 = g * 8;
      float s = b1[g];
#pragma unroll
      for (int j = 0; j < 8; ++j) {
        float t = xb[(size_t)(c0 + j) * HW_N + px];
        v[gg][j] = t;
        s += t * W1[g * 8 + j];
        am = fmaxf(am, fabsf(t));
      }
      fmT[g][px] = fmaxf(s, 0.0f);
    }
    lmax[chalf][px] = am;
  }
  __syncthreads();

  // ---- staging pass B: per-pixel scale + quantize to qxT ----
  {
    float amax = fmaxf(fmaxf(lmax[0][px], lmax[1][px]), 1e-30f);
    float inv  = 127.0f / amax;
    if (!chalf) sxT[px] = amax / 127.0f;
#pragma unroll
    for (int gr = 0; gr < 4; ++gr) {   // 4 granules of 16 channels each
      u32 pk[4];
#pragma unroll
      for (int q = 0; q < 4; ++q) {
        const int gg = gr * 2 + (q >> 1);
        const int j0 = (q & 1) * 4;
        pk[q] = pack4(v[gg][j0], v[gg][j0 + 1], v[gg][j0 + 2], v[gg][j0 + 3], inv);
      }
      int gidx = chalf * 4 + gr;
      int byte = px * 128 + ((gidx ^ (px & 7)) << 4);
      *reinterpret_cast<i32x4*>(qxT + byte) = *reinterpret_cast<i32x4*>(pk);
    }
  }
  __syncthreads();                     // qxT/fmT ready; slots 0,1 landed

  // ---- wave decomposition ----
  const int wm = w & 1;                // o offset 0/64
  const int wn = w >> 1;               // px offset 0/64
  const int lc = l & 15;
  const int lk = l >> 4;

  // ---- B-fragment register cache [ks2][nf] (group-invariant) ----
  i32x4 bfr[2][4];
#pragma unroll
  for (int ks2 = 0; ks2 < 2; ++ks2)
#pragma unroll
    for (int nf = 0; nf < 4; ++nf) {
      int p    = wn * 64 + nf * 16 + lc;
      int gidx = ks2 * 4 + lk;
      int byte = p * 128 + ((gidx ^ (p & 7)) << 4);
      bfr[ks2][nf] = *reinterpret_cast<const i32x4*>(qxT + byte);
    }

  f32x4 acc[4][4];
#pragma unroll
  for (int mf = 0; mf < 4; ++mf)
#pragma unroll
    for (int nf = 0; nf < 4; ++nf) acc[mf][nf] = (f32x4){0.f, 0.f, 0.f, 0.f};

  const char* abw = &Albs[0][0];
  const int   aoff = wm * 8192 + l * 16;

  // afr double-buffer (statically named, rule #20)
  i32x4 afrC[8], afrN[8];
#pragma unroll
  for (int mf = 0; mf < 4; ++mf) {     // afr(0) from slot 0
    afrC[mf * 2]     = *reinterpret_cast<const i32x4*>(abw + mf * 2048 + aoff);
    afrC[mf * 2 + 1] = *reinterpret_cast<const i32x4*>(abw + mf * 2048 + 1024 + aoff);
  }

#define GBODY(g, AC, AN)                                                     \
  {                                                                          \
    asm volatile("s_waitcnt lgkmcnt(0)" ::: "memory");  /* afr(g) sampled */ \
    asm volatile("s_waitcnt vmcnt(0)" ::: "memory");    /* stage(g+1) done */\
    __builtin_amdgcn_s_barrier();                                            \
    const char* abn = &Albs[((g) + 1) & 1][0];                               \
    _Pragma("unroll")                                                        \
    for (int mf = 0; mf < 4; ++mf) {   /* prefetch afr(g+1) */               \
      AN[mf * 2]     = *reinterpret_cast<const i32x4*>(abn + mf * 2048 + aoff);        \
      AN[mf * 2 + 1] = *reinterpret_cast<const i32x4*>(abn + mf * 2048 + 1024 + aoff); \
    }                                                                        \
    if ((g) + 2 < 16) stage((g) + 2, (g) & 1);                               \
    float sn[4];                                                             \
    _Pragma("unroll")                                                        \
    for (int nf = 0; nf < 4; ++nf) sn[nf] = fmT[g][wn * 64 + nf * 16 + lc];  \
    __builtin_amdgcn_s_setprio(1);                                           \
    _Pragma("unroll")                                                        \
    for (int nf = 0; nf < 4; ++nf) {                                         \
      i32x4 P[4];                                                            \
      _Pragma("unroll")                                                      \
      for (int mf = 0; mf < 4; ++mf)                                         \
        P[mf] = __builtin_amdgcn_mfma_i32_16x16x64_i8(                       \
            AC[mf * 2], bfr[0][nf], (i32x4){0, 0, 0, 0}, 0, 0, 0);           \
      _Pragma("unroll")                                                      \
      for (int mf = 0; mf < 4; ++mf)                                         \
        P[mf] = __builtin_amdgcn_mfma_i32_16x16x64_i8(                       \
            AC[mf * 2 + 1], bfr[1][nf], P[mf], 0, 0, 0);                     \
      _Pragma("unroll")                                                      \
      for (int mf = 0; mf < 4; ++mf) {                                       \
        _Pragma("unroll")                                                    \
        for (int i = 0; i < 4; ++i)                                          \
          acc[mf][nf][i] += sn[nf] * (float)P[mf][i];                        \
      }                                                                      \
    }                                                                        \
    __builtin_amdgcn_s_setprio(0);                                           \
  }

  // ---- main loop: 16 groups, unroll-2 (static afr C/N swap) ----
#pragma unroll 1
  for (int g = 0; g < 16; g += 2) {
    GBODY(g, afrC, afrN)
    GBODY(g + 1, afrN, afrC)
  }
#undef GBODY

  // ---- epilogue: out = acc*sw[o]*sx[p] + b2[o] ----
  float sxv[4];
#pragma unroll
  for (int nf = 0; nf < 4; ++nf) sxv[nf] = sxT[wn * 64 + nf * 16 + lc];
  float* outb = out + (size_t)b * O_N * HW_N + px0;
#pragma unroll
  for (int mf = 0; mf < 4; ++mf) {
    int o0 = mt * 128 + wm * 64 + mf * 16 + lk * 4;
#pragma unroll
    for (int i = 0; i < 4; ++i) {
      float so   = sw[o0 + i];
      float bias = b2[o0 + i];
#pragma unroll
      for (int nf = 0; nf < 4; ++nf) {
        int p = wn * 64 + nf * 16 + lc;
        outb[(size_t)(o0 + i) * HW_N + p] = acc[mf][nf][i] * so * sxv[nf] + bias;
      }
    }
  }
}

extern "C" void kernel_launch(void* const* d_in, const int* in_sizes, int n_in,
                              void* d_out, int out_size, void* d_ws, size_t ws_size,
                              hipStream_t stream) {
  const float* x  = (const float*)d_in[0];
  const float* W1 = (const float*)d_in[1];
  const float* b1 = (const float*)d_in[2];
  const float* W2 = (const float*)d_in[3];
  const float* b2 = (const float*)d_in[4];
  float* out = (float*)d_out;
  char*  w2q = (char*)d_ws;                       // 512 KB i8 tiled W2
  float* sw  = (float*)((char*)d_ws + 524288);    // 256 f32 row scales

  w2q_k<<<256, 64, 0, stream>>>(W2, w2q, sw);
  ccattn_main_k<<<512, 256, 0, stream>>>(x, W1, b1, w2q, sw, b2, out);
}

// Round 19
// 34.879 us; speedup vs baseline: 1.4297x; 1.0149x over previous
//
#include <hip/hip_runtime.h>

typedef float f32x4 __attribute__((ext_vector_type(4)));
typedef int   i32x4 __attribute__((ext_vector_type(4)));
typedef unsigned int u32;

#define HW_N  4096
#define C_N   128
#define G_N   16
#define K_N   2048
#define O_N   256
#define BN    128

typedef const __attribute__((address_space(1))) u32 gbl_u32;
typedef __attribute__((address_space(3))) u32 lds_u32;

__device__ __forceinline__ u32 pack4(float a, float b, float c, float d, float inv) {
  int q0 = (int)rintf(a * inv), q1 = (int)rintf(b * inv);
  int q2 = (int)rintf(c * inv), q3 = (int)rintf(d * inv);
  return (u32)(q0 & 255) | ((u32)(q1 & 255) << 8) |
         ((u32)(q2 & 255) << 16) | ((u32)(q3 & 255) << 24);
}

// ---- prep: W2 f32 [256][2048] -> i8, GROUP-MAJOR LDS image + row scale sw --
// byte = g*32768 + (o>>4)*2048 + ks2*1024 + lif*16,
// lif = (o&15) + ((k0>>4)&3)*16  (verified R17/R18: absmax 0.0703)
__global__ void w2q_k(const float* __restrict__ W2, char* __restrict__ w2q,
                      float* __restrict__ sw) {
  int o = blockIdx.x;                  // 0..255
  int l = threadIdx.x;                 // 0..63
  const f32x4* rp = reinterpret_cast<const f32x4*>(W2 + (size_t)o * K_N + l * 32);
  float v[32]; float am = 0.f;
#pragma unroll
  for (int q = 0; q < 8; ++q) {
    f32x4 t = rp[q];
#pragma unroll
    for (int j = 0; j < 4; ++j) { v[q * 4 + j] = t[j]; am = fmaxf(am, fabsf(t[j])); }
  }
#pragma unroll
  for (int s = 1; s < 64; s <<= 1) am = fmaxf(am, __shfl_xor(am, s, 64));
  am = fmaxf(am, 1e-30f);
  float inv = 127.0f / am;
  if (l == 0) sw[o] = am / 127.0f;
#pragma unroll
  for (int c = 0; c < 2; ++c) {
    int k0 = l * 32 + c * 16;
    u32 pk[4];
#pragma unroll
    for (int q = 0; q < 4; ++q)
      pk[q] = pack4(v[c * 16 + q * 4 + 0], v[c * 16 + q * 4 + 1],
                    v[c * 16 + q * 4 + 2], v[c * 16 + q * 4 + 3], inv);
    int g   = k0 >> 7;
    int ks2 = (k0 >> 6) & 1;
    int lif = (o & 15) + ((k0 >> 4) & 3) * 16;
    *reinterpret_cast<i32x4*>(w2q + (size_t)g * 32768 + (o >> 4) * 2048 +
                              ks2 * 1024 + lif * 16) = *reinterpret_cast<i32x4*>(pk);
  }
}

// ---- main fused kernel ----
// R18 + deferred fold: group g's 32 MFMAs issue as ONE burst into P;
// the fold of group g-1 runs in group g's preamble (after the barrier),
// covering afr(g)'s ds_read latency and leaving the matrix pipe free for
// the sibling wave. 3-slot A ring so stage(g+2) never hits a slot with
// in-flight ds_reads. 2 blocks/CU.
__launch_bounds__(256, 2)
__global__ void ccattn_main_k(const float* __restrict__ x,
                              const float* __restrict__ W1,
                              const float* __restrict__ b1,
                              const char* __restrict__ w2q,
                              const float* __restrict__ sw,
                              const float* __restrict__ b2,
                              float* __restrict__ out) {
  __shared__ __align__(16) char Albs[3][16384];   // 48 KB A ring
  __shared__ char  qxT[BN * 128];      // 16 KB, [px][c] i8, granule-swizzled
  __shared__ float fmT[G_N][BN];       // 8 KB
  __shared__ float sxT[BN];
  __shared__ float lmax[2][BN];

  const int tid = threadIdx.x;
  const int bid = blockIdx.x;
  const int mt  = bid >> 8;            // pt-major: co-resident blocks share mt
  const int pt  = bid & 255;
  const int b   = pt >> 5;
  const int px0 = (pt & 31) * BN;

  const int w = tid >> 6;
  const int l = tid & 63;

  // stage group g's 16 KB A tile (this block's mt half): 4 x 1 KB per wave
  auto stage = [&](int g, int slot) {
    const char* src = w2q + (size_t)g * 32768 + mt * 16384 + w * 4096 + l * 16;
    char* dst = &Albs[slot][w * 4096];
#pragma unroll
    for (int r = 0; r < 4; ++r)
      __builtin_amdgcn_global_load_lds((gbl_u32*)(src + r * 1024),
                                       (lds_u32*)(dst + r * 1024), 16, 0, 0);
  };
  stage(0, 0);                         // in flight under x staging
  stage(1, 1);

  const float* xb = x + (size_t)b * C_N * HW_N + px0;

  // ---- staging pass A: read x (exact f32), fm, per-half absmax ----
  const int px    = tid & 127;
  const int chalf = tid >> 7;          // channels [0,64) or [64,128)
  float v[8][8];
  {
    float am = 0.f;
#pragma unroll
    for (int gg = 0; gg < 8; ++gg) {
      const int g  = chalf * 8 + gg;
      const int c0 = g * 8;
      float s = b1[g];
#pragma unroll
      for (int j = 0; j < 8; ++j) {
        float t = xb[(size_t)(c0 + j) * HW_N + px];
        v[gg][j] = t;
        s += t * W1[g * 8 + j];
        am = fmaxf(am, fabsf(t));
      }
      fmT[g][px] = fmaxf(s, 0.0f);
    }
    lmax[chalf][px] = am;
  }
  __syncthreads();

  // ---- staging pass B: per-pixel scale + quantize to qxT ----
  {
    float amax = fmaxf(fmaxf(lmax[0][px], lmax[1][px]), 1e-30f);
    float inv  = 127.0f / amax;
    if (!chalf) sxT[px] = amax / 127.0f;
#pragma unroll
    for (int gr = 0; gr < 4; ++gr) {   // 4 granules of 16 channels each
      u32 pk[4];
#pragma unroll
      for (int q = 0; q < 4; ++q) {
        const int gg = gr * 2 + (q >> 1);
        const int j0 = (q & 1) * 4;
        pk[q] = pack4(v[gg][j0], v[gg][j0 + 1], v[gg][j0 + 2], v[gg][j0 + 3], inv);
      }
      int gidx = chalf * 4 + gr;
      int byte = px * 128 + ((gidx ^ (px & 7)) << 4);
      *reinterpret_cast<i32x4*>(qxT + byte) = *reinterpret_cast<i32x4*>(pk);
    }
  }
  __syncthreads();                     // qxT/fmT ready; slots 0,1 landed (drain)

  // ---- wave decomposition ----
  const int wm = w & 1;                // o offset 0/64
  const int wn = w >> 1;               // px offset 0/64
  const int lc = l & 15;
  const int lk = l >> 4;

  // ---- B-fragment register cache [ks2][nf] (group-invariant) ----
  i32x4 bfr[2][4];
#pragma unroll
  for (int ks2 = 0; ks2 < 2; ++ks2)
#pragma unroll
    for (int nf = 0; nf < 4; ++nf) {
      int p    = wn * 64 + nf * 16 + lc;
      int gidx = ks2 * 4 + lk;
      int byte = p * 128 + ((gidx ^ (p & 7)) << 4);
      bfr[ks2][nf] = *reinterpret_cast<const i32x4*>(qxT + byte);
    }

  f32x4 acc[4][4];
#pragma unroll
  for (int mf = 0; mf < 4; ++mf)
#pragma unroll
    for (int nf = 0; nf < 4; ++nf) acc[mf][nf] = (f32x4){0.f, 0.f, 0.f, 0.f};

  const int aoff = wm * 8192 + l * 16;

  i32x4 afr[8];                        // single A fragment buffer
  i32x4 P[4][4];                       // deferred-fold MFMA results
  float snP[4];                        // fm scales of the group held in P

  // ---- main loop: 16 groups; fold(g-1) deferred into g's preamble ----
#pragma unroll 1
  for (int g = 0; g < 16; ++g) {
    // my afr/sn reads of group g-1 completed; my stage(g+1) landed
    asm volatile("s_waitcnt lgkmcnt(0)" ::: "memory");
    asm volatile("s_waitcnt vmcnt(0)" ::: "memory");
    __builtin_amdgcn_s_barrier();
    // slot g%3 was published at body(g-1)'s barrier; read this group's A
    const char* ab = &Albs[g % 3][0];
#pragma unroll
    for (int mf = 0; mf < 4; ++mf) {
      afr[mf * 2]     = *reinterpret_cast<const i32x4*>(ab + mf * 2048 + aoff);
      afr[mf * 2 + 1] = *reinterpret_cast<const i32x4*>(ab + mf * 2048 + 1024 + aoff);
    }
    float snC[4];
#pragma unroll
    for (int nf = 0; nf < 4; ++nf) snC[nf] = fmT[g][wn * 64 + nf * 16 + lc];
    // stage(g+2) -> slot (g+2)%3 == slot (g-1)%3: all reads of it finished
    // (every wave's lgkmcnt(0) preceded the barrier above)
    if (g + 2 < 16) stage(g + 2, (g + 2) % 3);

    // deferred fold of group g-1 (no dependency on this group's MFMAs;
    // covers afr ds_read latency; sibling wave owns the matrix pipe)
    if (g > 0) {
#pragma unroll
      for (int mf = 0; mf < 4; ++mf)
#pragma unroll
        for (int nf = 0; nf < 4; ++nf) {
#pragma unroll
          for (int i = 0; i < 4; ++i)
            acc[mf][nf][i] += snP[nf] * (float)P[mf][nf][i];
        }
    }
#pragma unroll
    for (int nf = 0; nf < 4; ++nf) snP[nf] = snC[nf];

    // MFMA burst: 32 back-to-back, one dependency pair per (mf,nf)
    __builtin_amdgcn_s_setprio(1);
#pragma unroll
    for (int nf = 0; nf < 4; ++nf)
#pragma unroll
      for (int mf = 0; mf < 4; ++mf)
        P[mf][nf] = __builtin_amdgcn_mfma_i32_16x16x64_i8(
            afr[mf * 2], bfr[0][nf], (i32x4){0, 0, 0, 0}, 0, 0, 0);
#pragma unroll
    for (int nf = 0; nf < 4; ++nf)
#pragma unroll
      for (int mf = 0; mf < 4; ++mf)
        P[mf][nf] = __builtin_amdgcn_mfma_i32_16x16x64_i8(
            afr[mf * 2 + 1], bfr[1][nf], P[mf][nf], 0, 0, 0);
    __builtin_amdgcn_s_setprio(0);
  }

  // tail fold of group 15
#pragma unroll
  for (int mf = 0; mf < 4; ++mf)
#pragma unroll
    for (int nf = 0; nf < 4; ++nf) {
#pragma unroll
      for (int i = 0; i < 4; ++i)
        acc[mf][nf][i] += snP[nf] * (float)P[mf][nf][i];
    }

  // ---- epilogue: out = acc*sw[o]*sx[p] + b2[o] ----
  float sxv[4];
#pragma unroll
  for (int nf = 0; nf < 4; ++nf) sxv[nf] = sxT[wn * 64 + nf * 16 + lc];
  float* outb = out + (size_t)b * O_N * HW_N + px0;
#pragma unroll
  for (int mf = 0; mf < 4; ++mf) {
    int o0 = mt * 128 + wm * 64 + mf * 16 + lk * 4;
#pragma unroll
    for (int i = 0; i < 4; ++i) {
      float so   = sw[o0 + i];
      float bias = b2[o0 + i];
#pragma unroll
      for (int nf = 0; nf < 4; ++nf) {
        int p = wn * 64 + nf * 16 + lc;
        outb[(size_t)(o0 + i) * HW_N + p] = acc[mf][nf][i] * so * sxv[nf] + bias;
      }
    }
  }
}

extern "C" void kernel_launch(void* const* d_in, const int* in_sizes, int n_in,
                              void* d_out, int out_size, void* d_ws, size_t ws_size,
                              hipStream_t stream) {
  const float* x  = (const float*)d_in[0];
  const float* W1 = (const float*)d_in[1];
  const float* b1 = (const float*)d_in[2];
  const float* W2 = (const float*)d_in[3];
  const float* b2 = (const float*)d_in[4];
  float* out = (float*)d_out;
  char*  w2q = (char*)d_ws;                       // 512 KB i8 tiled W2
  float* sw  = (float*)((char*)d_ws + 524288);    // 256 f32 row scales

  w2q_k<<<256, 64, 0, stream>>>(W2, w2q, sw);
  ccattn_main_k<<<512, 256, 0, stream>>>(x, W1, b1, w2q, sw, b2, out);
}

// Round 20
// 34.752 us; speedup vs baseline: 1.4349x; 1.0036x over previous
//
#include <hip/hip_runtime.h>

typedef float f32x4 __attribute__((ext_vector_type(4)));
typedef float f32x2 __attribute__((ext_vector_type(2)));
typedef int   i32x4 __attribute__((ext_vector_type(4)));
typedef unsigned int u32;

#define HW_N  4096
#define C_N   128
#define G_N   16
#define K_N   2048
#define O_N   256
#define BN    128

typedef const __attribute__((address_space(1))) u32 gbl_u32;
typedef __attribute__((address_space(3))) u32 lds_u32;

__device__ __forceinline__ u32 pack4(float a, float b, float c, float d, float inv) {
  int q0 = (int)rintf(a * inv), q1 = (int)rintf(b * inv);
  int q2 = (int)rintf(c * inv), q3 = (int)rintf(d * inv);
  return (u32)(q0 & 255) | ((u32)(q1 & 255) << 8) |
         ((u32)(q2 & 255) << 16) | ((u32)(q3 & 255) << 24);
}

// ---- prep: W2 f32 [256][2048] -> i8, GROUP-MAJOR LDS image + row scale sw --
// byte = g*32768 + (o>>4)*2048 + ks2*1024 + lif*16,
// lif = (o&15) + ((k0>>4)&3)*16  (layout verified R17-R19: absmax 0.0703)
// 256 blocks x 128 threads: one row per block, 2 waves splitting K.
__global__ void w2q_k(const float* __restrict__ W2, char* __restrict__ w2q,
                      float* __restrict__ sw) {
  __shared__ float amW[2];
  int o = blockIdx.x;                  // 0..255
  int w = threadIdx.x >> 6;            // K-half
  int l = threadIdx.x & 63;
  // lane covers 16 consecutive floats: k0 = w*1024 + l*16
  const f32x4* rp = reinterpret_cast<const f32x4*>(W2 + (size_t)o * K_N + w * 1024 + l * 16);
  float v[16]; float am = 0.f;
#pragma unroll
  for (int q = 0; q < 4; ++q) {
    f32x4 t = rp[q];
#pragma unroll
    for (int j = 0; j < 4; ++j) { v[q * 4 + j] = t[j]; am = fmaxf(am, fabsf(t[j])); }
  }
#pragma unroll
  for (int s = 1; s < 64; s <<= 1) am = fmaxf(am, __shfl_xor(am, s, 64));
  if (l == 0) amW[w] = am;
  __syncthreads();
  am = fmaxf(fmaxf(amW[0], amW[1]), 1e-30f);
  float inv = 127.0f / am;
  if (threadIdx.x == 0) sw[o] = am / 127.0f;
  int k0 = w * 1024 + l * 16;
  u32 pk[4];
#pragma unroll
  for (int q = 0; q < 4; ++q)
    pk[q] = pack4(v[q * 4 + 0], v[q * 4 + 1], v[q * 4 + 2], v[q * 4 + 3], inv);
  int g   = k0 >> 7;
  int ks2 = (k0 >> 6) & 1;
  int lif = (o & 15) + ((k0 >> 4) & 3) * 16;
  *reinterpret_cast<i32x4*>(w2q + (size_t)g * 32768 + (o >> 4) * 2048 +
                            ks2 * 1024 + lif * 16) = *reinterpret_cast<i32x4*>(pk);
}

// ---- main fused kernel (R19 structure; fold in float2 pairs) ----
__launch_bounds__(256, 2)
__global__ void ccattn_main_k(const float* __restrict__ x,
                              const float* __restrict__ W1,
                              const float* __restrict__ b1,
                              const char* __restrict__ w2q,
                              const float* __restrict__ sw,
                              const float* __restrict__ b2,
                              float* __restrict__ out) {
  __shared__ __align__(16) char Albs[3][16384];   // 48 KB A ring
  __shared__ char  qxT[BN * 128];      // 16 KB, [px][c] i8, granule-swizzled
  __shared__ float fmT[G_N][BN];       // 8 KB
  __shared__ float sxT[BN];
  __shared__ float lmax[2][BN];

  const int tid = threadIdx.x;
  const int bid = blockIdx.x;
  const int mt  = bid >> 8;            // pt-major: co-resident blocks share mt
  const int pt  = bid & 255;
  const int b   = pt >> 5;
  const int px0 = (pt & 31) * BN;

  const int w = tid >> 6;
  const int l = tid & 63;

  auto stage = [&](int g, int slot) {
    const char* src = w2q + (size_t)g * 32768 + mt * 16384 + w * 4096 + l * 16;
    char* dst = &Albs[slot][w * 4096];
#pragma unroll
    for (int r = 0; r < 4; ++r)
      __builtin_amdgcn_global_load_lds((gbl_u32*)(src + r * 1024),
                                       (lds_u32*)(dst + r * 1024), 16, 0, 0);
  };
  stage(0, 0);                         // in flight under x staging
  stage(1, 1);

  const float* xb = x + (size_t)b * C_N * HW_N + px0;

  // ---- staging pass A: read x (exact f32), fm, per-half absmax ----
  const int px    = tid & 127;
  const int chalf = tid >> 7;
  float v[8][8];
  {
    float am = 0.f;
#pragma unroll
    for (int gg = 0; gg < 8; ++gg) {
      const int g  = chalf * 8 + gg;
      const int c0 = g * 8;
      float s = b1[g];
#pragma unroll
      for (int j = 0; j < 8; ++j) {
        float t = xb[(size_t)(c0 + j) * HW_N + px];
        v[gg][j] = t;
        s += t * W1[g * 8 + j];
        am = fmaxf(am, fabsf(t));
      }
      fmT[g][px] = fmaxf(s, 0.0f);
    }
    lmax[chalf][px] = am;
  }
  __syncthreads();

  // ---- staging pass B: per-pixel scale + quantize to qxT ----
  {
    float amax = fmaxf(fmaxf(lmax[0][px], lmax[1][px]), 1e-30f);
    float inv  = 127.0f / amax;
    if (!chalf) sxT[px] = amax / 127.0f;
#pragma unroll
    for (int gr = 0; gr < 4; ++gr) {
      u32 pk[4];
#pragma unroll
      for (int q = 0; q < 4; ++q) {
        const int gg = gr * 2 + (q >> 1);
        const int j0 = (q & 1) * 4;
        pk[q] = pack4(v[gg][j0], v[gg][j0 + 1], v[gg][j0 + 2], v[gg][j0 + 3], inv);
      }
      int gidx = chalf * 4 + gr;
      int byte = px * 128 + ((gidx ^ (px & 7)) << 4);
      *reinterpret_cast<i32x4*>(qxT + byte) = *reinterpret_cast<i32x4*>(pk);
    }
  }
  __syncthreads();                     // qxT/fmT ready; slots 0,1 landed (drain)

  // ---- wave decomposition ----
  const int wm = w & 1;
  const int wn = w >> 1;
  const int lc = l & 15;
  const int lk = l >> 4;

  // ---- B-fragment register cache [ks2][nf] (group-invariant) ----
  i32x4 bfr[2][4];
#pragma unroll
  for (int ks2 = 0; ks2 < 2; ++ks2)
#pragma unroll
    for (int nf = 0; nf < 4; ++nf) {
      int p    = wn * 64 + nf * 16 + lc;
      int gidx = ks2 * 4 + lk;
      int byte = p * 128 + ((gidx ^ (p & 7)) << 4);
      bfr[ks2][nf] = *reinterpret_cast<const i32x4*>(qxT + byte);
    }

  f32x4 acc[4][4];
#pragma unroll
  for (int mf = 0; mf < 4; ++mf)
#pragma unroll
    for (int nf = 0; nf < 4; ++nf) acc[mf][nf] = (f32x4){0.f, 0.f, 0.f, 0.f};

  const int aoff = wm * 8192 + l * 16;

  i32x4 afr[8];
  i32x4 P[4][4];
  float snP[4];

  // ---- main loop: 16 groups; fold(g-1) deferred into g's preamble ----
#pragma unroll 1
  for (int g = 0; g < 16; ++g) {
    asm volatile("s_waitcnt lgkmcnt(0)" ::: "memory");
    asm volatile("s_waitcnt vmcnt(0)" ::: "memory");
    __builtin_amdgcn_s_barrier();
    const char* ab = &Albs[g % 3][0];
#pragma unroll
    for (int mf = 0; mf < 4; ++mf) {
      afr[mf * 2]     = *reinterpret_cast<const i32x4*>(ab + mf * 2048 + aoff);
      afr[mf * 2 + 1] = *reinterpret_cast<const i32x4*>(ab + mf * 2048 + 1024 + aoff);
    }
    float snC[4];
#pragma unroll
    for (int nf = 0; nf < 4; ++nf) snC[nf] = fmT[g][wn * 64 + nf * 16 + lc];
    if (g + 2 < 16) stage(g + 2, (g + 2) % 3);

    // deferred fold of group g-1, float2 pairs (targets v_pk_fma_f32)
    if (g > 0) {
#pragma unroll
      for (int mf = 0; mf < 4; ++mf)
#pragma unroll
        for (int nf = 0; nf < 4; ++nf) {
          f32x2 s2 = {snP[nf], snP[nf]};
          f32x2 p0 = {(float)P[mf][nf][0], (float)P[mf][nf][1]};
          f32x2 p1 = {(float)P[mf][nf][2], (float)P[mf][nf][3]};
          f32x2 a0 = {acc[mf][nf][0], acc[mf][nf][1]};
          f32x2 a1 = {acc[mf][nf][2], acc[mf][nf][3]};
          a0 += s2 * p0;
          a1 += s2 * p1;
          acc[mf][nf][0] = a0[0]; acc[mf][nf][1] = a0[1];
          acc[mf][nf][2] = a1[0]; acc[mf][nf][3] = a1[1];
        }
    }
#pragma unroll
    for (int nf = 0; nf < 4; ++nf) snP[nf] = snC[nf];

    __builtin_amdgcn_s_setprio(1);
#pragma unroll
    for (int nf = 0; nf < 4; ++nf)
#pragma unroll
      for (int mf = 0; mf < 4; ++mf)
        P[mf][nf] = __builtin_amdgcn_mfma_i32_16x16x64_i8(
            afr[mf * 2], bfr[0][nf], (i32x4){0, 0, 0, 0}, 0, 0, 0);
#pragma unroll
    for (int nf = 0; nf < 4; ++nf)
#pragma unroll
      for (int mf = 0; mf < 4; ++mf)
        P[mf][nf] = __builtin_amdgcn_mfma_i32_16x16x64_i8(
            afr[mf * 2 + 1], bfr[1][nf], P[mf][nf], 0, 0, 0);
    __builtin_amdgcn_s_setprio(0);
  }

  // tail fold of group 15
#pragma unroll
  for (int mf = 0; mf < 4; ++mf)
#pragma unroll
    for (int nf = 0; nf < 4; ++nf) {
#pragma unroll
      for (int i = 0; i < 4; ++i)
        acc[mf][nf][i] += snP[nf] * (float)P[mf][nf][i];
    }

  // ---- epilogue: out = acc*sw[o]*sx[p] + b2[o] ----
  float sxv[4];
#pragma unroll
  for (int nf = 0; nf < 4; ++nf) sxv[nf] = sxT[wn * 64 + nf * 16 + lc];
  float* outb = out + (size_t)b * O_N * HW_N + px0;
#pragma unroll
  for (int mf = 0; mf < 4; ++mf) {
    int o0 = mt * 128 + wm * 64 + mf * 16 + lk * 4;
#pragma unroll
    for (int i = 0; i < 4; ++i) {
      float so   = sw[o0 + i];
      float bias = b2[o0 + i];
#pragma unroll
      for (int nf = 0; nf < 4; ++nf) {
        int p = wn * 64 + nf * 16 + lc;
        outb[(size_t)(o0 + i) * HW_N + p] = acc[mf][nf][i] * so * sxv[nf] + bias;
      }
    }
  }
}

extern "C" void kernel_launch(void* const* d_in, const int* in_sizes, int n_in,
                              void* d_out, int out_size, void* d_ws, size_t ws_size,
                              hipStream_t stream) {
  const float* x  = (const float*)d_in[0];
  const float* W1 = (const float*)d_in[1];
  const float* b1 = (const float*)d_in[2];
  const float* W2 = (const float*)d_in[3];
  const float* b2 = (const float*)d_in[4];
  float* out = (float*)d_out;
  char*  w2q = (char*)d_ws;                       // 512 KB i8 tiled W2
  float* sw  = (float*)((char*)d_ws + 524288);    // 256 f32 row scales

  w2q_k<<<256, 128, 0, stream>>>(W2, w2q, sw);
  ccattn_main_k<<<512, 256, 0, stream>>>(x, W1, b1, w2q, sw, b2, out);
}